// Round 8
// baseline (349.910 us; speedup 1.0000x reference)
//
#include <hip/hip_runtime.h>
#include <math.h>

#define SCALE_ 0.125f

typedef unsigned short u16;
typedef __attribute__((ext_vector_type(8))) _Float16 half8;
typedef __attribute__((ext_vector_type(4))) float f32x4;
#define MFMA_H __builtin_amdgcn_mfma_f32_16x16x32_f16

__device__ __forceinline__ u16 f2h(float f) {
    union { _Float16 h; u16 u; } v; v.h = (_Float16)f; return v.u;
}
__device__ __forceinline__ float h2f(u16 u) {
    union { _Float16 h; u16 u; } v; v.u = u; return (float)v.h;
}
__device__ __forceinline__ void gload16(const u16* g, u16* l) {
    __builtin_amdgcn_global_load_lds(
        (const __attribute__((address_space(1))) void*)g,
        (__attribute__((address_space(3))) void*)l, 16, 0, 0);
}
__device__ __forceinline__ half8 ld_h8(const u16* p) {
    return *(const half8*)p;
}

// ---------------------------------------------------------------------------
// prep_all: all input-prep fused into one grid-sectioned kernel.
//   sect A [0,4728)      : x -> f16
//   sect B [4728,5304)   : transpose weights Wt[n][k] f16 (4 weights x 12x12)
//   sect C1 [5304,5320)  : tk[r][d] f16 (rel_k tables, padded rows)
//   sect C2 [5320,5348)  : gt[g][j] 32x224 indicator (value-bias histogram)
//   sect C3 [5348,5376)  : khot[j][c] 224x32 one-hot (key-bias K-augment)
//   sect D [5376,6144)   : vt const cols 197..287 per bh
// ---------------------------------------------------------------------------
__global__ void prep_all(const float* __restrict__ x,
                         const float* __restrict__ w0, const float* __restrict__ w1,
                         const float* __restrict__ w2, const float* __restrict__ w3,
                         const float* __restrict__ rkv, const float* __restrict__ rkh,
                         const float* __restrict__ rvv, const float* __restrict__ rvh,
                         u16* __restrict__ xh,
                         u16* o0, u16* o1, u16* o2, u16* o3,
                         u16* __restrict__ tk, u16* __restrict__ gt,
                         u16* __restrict__ khot, u16* __restrict__ vtp) {
    __shared__ float t[64 * 68];
    int b = blockIdx.x;
    const int tid = threadIdx.x;

    if (b < 4728) {                       // ---- sect A: x -> f16
        size_t idx = ((size_t)b * 256 + tid) * 8;
        float4 a = *(const float4*)(x + idx), bb = *(const float4*)(x + idx + 4);
        float f[8] = {a.x, a.y, a.z, a.w, bb.x, bb.y, bb.z, bb.w};
        u16 hs[8];
        #pragma unroll
        for (int e = 0; e < 8; ++e) hs[e] = f2h(f[e]);
        *(uint4*)(xh + idx) = *(uint4*)hs;
        return;
    }
    b -= 4728;
    if (b < 576) {                        // ---- sect B: weight transpose
        int z = b / 144, rem = b - z * 144;
        int by = rem / 12, bx = rem - by * 12;
        const float* W; u16* oh;
        if (z == 0)      { W = w0; oh = o0; }
        else if (z == 1) { W = w1; oh = o1; }
        else if (z == 2) { W = w2; oh = o2; }
        else             { W = w3; oh = o3; }
        int k0 = by * 64, n0 = bx * 64;
        #pragma unroll
        for (int rr = 0; rr < 4; ++rr) {
            int r = (tid >> 4) + rr * 16;
            int c = (tid & 15) * 4;
            *(float4*)&t[r * 68 + c] = *(const float4*)(W + (size_t)(k0 + r) * 768 + n0 + c);
        }
        __syncthreads();
        int n = tid >> 2, kc = (tid & 3) * 16;
        u16 hs[16];
        #pragma unroll
        for (int e = 0; e < 16; ++e) hs[e] = f2h(t[(kc + e) * 68 + n]);
        size_t o = (size_t)(n0 + n) * 768 + k0 + kc;
        *(uint4*)(oh + o) = *(uint4*)hs;
        *(uint4*)(oh + o + 8) = *(uint4*)(hs + 8);
        return;
    }
    b -= 576;
    if (b < 16) {                         // ---- sect C1: tk
        int idx = b * 256 + tid;          // 0..4095
        int r = idx >> 6, d = idx & 63;
        float tv = 0.f;
        if (r < 30) tv = rkv[r * 64 + d];
        else if (r >= 32 && r < 62) tv = rkh[(r - 32) * 64 + d];
        tk[idx] = f2h(tv);
        return;
    }
    b -= 16;
    if (b < 28) {                         // ---- sect C2: gt
        int idx = b * 256 + tid;          // 0..7167
        int g = idx / 224, j = idx - (idx / 224) * 224;
        float v = 0.f;
        if (j >= 1 && j < 197) {
            int jq = j - 1;
            int jv = jq / 14, jh = jq - jv * 14;
            if (g < 14) v = (jv == g) ? 1.f : 0.f;
            else if (g >= 16 && g < 30) v = (jh == g - 16) ? 1.f : 0.f;
        }
        gt[idx] = f2h(v);
        return;
    }
    b -= 28;
    if (b < 28) {                         // ---- sect C3: khot
        int idx = b * 256 + tid;          // 0..7167
        int j = idx >> 5, c = idx & 31;
        float v = 0.f;
        if (j >= 1 && j < 197) {
            int jq = j - 1;
            int jv = jq / 14, jh = jq - jv * 14;
            if (c < 14) v = (jv == c) ? 1.f : 0.f;
            else if (c < 28) v = (jh == c - 14) ? 1.f : 0.f;
        }
        khot[idx] = f2h(v);
        return;
    }
    b -= 28;
    {                                     // ---- sect D: vt const part, bh = b
        u16* vb = vtp + (size_t)b * 64 * 288;
        for (int tt = tid; tt < 64 * 91; tt += 256) {
            int d = tt / 91;
            int c = 197 + (tt - d * 91);
            u16 val = 0;
            if (c >= 208 && c < 272) {
                int rr = c - 208;
                float v = 0.f;
                if (rr < 30) v = rvv[rr * 64 + d];
                else if (rr >= 32 && rr < 62) v = rvh[(rr - 32) * 64 + d];
                val = f2h(v);
            }
            vb[d * 288 + c] = val;
        }
    }
}

// ---------------------------------------------------------------------------
// Single-pass f16 MFMA GEMM, XCD-grouped work mapping, BK=64, LDS-bounce
// epilogue. C(12608,768) = A @ B + bias; A f16 row-major, B as Bt[n][k] f16.
// kind 0: z=0/1 -> q/k row-major scatter; z=2 -> V written TRANSPOSED
// directly into vt[bh][d][288] (vtrans kernel fused away). kind 1: fp32 out.
// ---------------------------------------------------------------------------
__global__ __launch_bounds__(256, 4) void gemm_f16(
    const u16* __restrict__ Ah,
    const u16* __restrict__ B0, const u16* __restrict__ B1, const u16* __restrict__ B2,
    const float* __restrict__ bias0, const float* __restrict__ bias1,
    const float* __restrict__ bias2,
    u16* qo, u16* ko, u16* vo, float* outf, int nz, int kind)
{
    __shared__ u16 SM[128 * 64 * 2];
    u16* As = SM;
    u16* Bs = SM + 128 * 64;

    const int p = blockIdx.x;
    const int xcd = p & 7, s = p >> 3;
    const int mcnt = (xcd < 3) ? 13 : 12;
    const int mbase = (xcd < 3) ? xcd * 13 : 39 + (xcd - 3) * 12;
    const int jn = 6 * nz;
    if (s >= mcnt * jn) return;
    const int mb = mbase + s / jn;
    const int j = s % jn;
    const int z = j / 6;
    const int nb = j % 6;

    const u16* Bt = B0; const float* bias = bias0;
    if (z == 1) { Bt = B1; bias = bias1; }
    else if (z == 2) { Bt = B2; bias = bias2; }

    const int m0 = mb * 128, n0 = nb * 128;
    const int tid = threadIdx.x;
    const int w = tid >> 6, lane = tid & 63, quad = lane >> 4, l16 = lane & 15;
    const int wm = (w >> 1) * 64, wn = (w & 1) * 64;
    const int rl8 = lane >> 3, cs = lane & 7;
    const int csrc = (cs ^ rl8) * 8;

    f32x4 acc[4][4];
    #pragma unroll
    for (int a = 0; a < 4; ++a)
        #pragma unroll
        for (int b = 0; b < 4; ++b) acc[a][b] = (f32x4){0, 0, 0, 0};

    for (int kt = 0; kt < 768; kt += 64) {
        __syncthreads();
        #pragma unroll
        for (int i = 0; i < 4; ++i) {
            int r = w * 32 + i * 8 + rl8;
            int arow = min(m0 + r, 12607);
            gload16(Ah + (size_t)arow * 768 + kt + csrc, &As[(w * 32 + i * 8) * 64]);
            gload16(Bt + (size_t)(n0 + r) * 768 + kt + csrc, &Bs[(w * 32 + i * 8) * 64]);
        }
        __syncthreads();
        #pragma unroll
        for (int kb = 0; kb < 2; ++kb) {
            const int slot = ((kb * 4 + quad) ^ (l16 & 7)) * 8;
            half8 ah[4], bf[4];
            #pragma unroll
            for (int mi = 0; mi < 4; ++mi) {
                ah[mi] = ld_h8(&As[(wm + mi * 16 + l16) * 64 + slot]);
                bf[mi] = ld_h8(&Bs[(wn + mi * 16 + l16) * 64 + slot]);
            }
            #pragma unroll
            for (int ni = 0; ni < 4; ++ni)
                #pragma unroll
                for (int mi = 0; mi < 4; ++mi)
                    acc[mi][ni] = MFMA_H(ah[mi], bf[ni], acc[mi][ni], 0, 0, 0);
        }
    }

    if (kind == 1) {
        #pragma unroll
        for (int mi = 0; mi < 4; ++mi) {
            #pragma unroll
            for (int r = 0; r < 4; ++r) {
                int gr = m0 + wm + mi * 16 + quad * 4 + r;
                if (gr >= 12608) continue;
                #pragma unroll
                for (int ni = 0; ni < 4; ++ni) {
                    int gc = n0 + wn + ni * 16 + l16;
                    outf[(size_t)gr * 768 + gc] = acc[mi][ni][r] + bias[gc];
                }
            }
        }
        return;
    }

    // ---- LDS-bounce epilogue: Cs[128][128] u16 (overlays As/Bs)
    __syncthreads();
    u16* Cs = SM;
    #pragma unroll
    for (int mi = 0; mi < 4; ++mi) {
        #pragma unroll
        for (int ni = 0; ni < 4; ++ni) {
            int col = wn + ni * 16 + l16;
            float bv = bias[n0 + col];
            #pragma unroll
            for (int r = 0; r < 4; ++r)
                Cs[(wm + mi * 16 + quad * 4 + r) * 128 + col] = f2h(acc[mi][ni][r] + bv);
        }
    }
    __syncthreads();

    if (z == 2) {
        // ---- fused V-transpose: Cs[key][chalf*64+d] -> vt[bh][d][288]+key
        // thread = (k2 = key-in-tile, chalf = head half); d rotated by lane
        // so Cs reads stay 2-way bank-free; stores are 2B (no alignment
        // constraint from ii = gr % 197).
        int k2 = tid & 127, chalf = tid >> 7;
        int gr = m0 + k2;
        if (gr < 12608) {
            int bb = gr / 197, ii = gr - bb * 197;
            int h = (n0 >> 6) + chalf;
            u16* vbase = vo + ((size_t)(bb * 12 + h) * 64) * 288 + ii;
            #pragma unroll
            for (int dd = 0; dd < 64; ++dd) {
                int d = (dd + (k2 & 63)) & 63;
                vbase[(size_t)d * 288] = Cs[k2 * 128 + chalf * 64 + d];
            }
        }
        return;
    }

    u16* O = (z == 0) ? qo : ko;
    int row = tid >> 1, halfc = tid & 1;
    int gr = m0 + row;
    if (gr < 12608) {
        int bb = gr / 197, ii = gr - bb * 197;
        int h = (n0 >> 6) + halfc;
        u16* dst = O + ((size_t)(bb * 12 + h) * 197 + ii) * 64;
        const u16* src = &Cs[row * 128 + halfc * 64];
        #pragma unroll
        for (int e = 0; e < 8; ++e)
            *(uint4*)(dst + e * 8) = *(const uint4*)(src + e * 8);
    }
}

// ---------------------------------------------------------------------------
// Fused attention, single-pass f16 MFMA, register-resident scores.
// XCD-grouped: 4 qt-blocks of one bh run adjacent on one XCD.
// K staged to LDS via global_load_lds DIRECT (zero staging VGPRs): LDS is
// linear [224][64], bank-freedom recovered by pre-swizzling the SOURCE col
// (chunk ^ (row&7)) and reading with the same XOR (rule: swizzle both sides
// or neither). Rows 197..223 zeroed by ds writes (they feed the row max).
// R6->R7 lesson: kreg[4]+manual LDS writes cost 16 VGPR -> ~9MB scratch
// spill; gload_lds removes that pressure.
// iRPE key bias via K-augmentation (khot one-hot MFMA), khot register-
// prefetched (R5 lesson). launch_bounds 2nd arg = min BLOCKS/CU here.
// ---------------------------------------------------------------------------
__global__ __launch_bounds__(512, 3) void attn_mfma(
    const u16* __restrict__ qh, const u16* __restrict__ kh,
    const u16* __restrict__ tk, const u16* __restrict__ vt,
    const u16* __restrict__ gt, const u16* __restrict__ khot,
    u16* __restrict__ oh)
{
    __shared__ u16 Ph[64 * 296];      // 37888 B; first used as Kst[224][64] = 28672 B
    __shared__ float BsT[64 * 36];    // 9216 B: phase A = Tvh f16; phase B = Bs f32
    __shared__ float red[64 * 4];     // [m][max0,max1,sum0,sum1]
    u16* Tvh16 = (u16*)BsT;           // 64*68 u16 = 8704 B
    u16* Kst = Ph;                    // overlay: K staging, dead before first Ph write

    const int p = blockIdx.x;
    const int xcd = p & 7, s = p >> 3;
    const int bh = xcd * 96 + (s >> 2);
    const int qt = s & 3;
    const int I0 = qt * 64;
    const int tid = threadIdx.x;
    const int w = tid >> 6, lane = tid & 63, quad = lane >> 4, l16 = lane & 15;
    const int mf = w >> 1, nh = w & 1;
    const int mr0 = mf * 16;
    const size_t base = (size_t)bh * 197 * 64;
    const uint4 z4 = make_uint4(0, 0, 0, 0);

    // ---- issue Q A-frag loads + khot prefetch + K->LDS gload (independent,
    //      in flight under phase 0's MFMAs)
    half8 qa[2];
    {
        int i = I0 + mr0 + l16;
        bool ok = i < 197;
        const u16* qp = qh + base + (size_t)i * 64 + quad * 8;
        #pragma unroll
        for (int kb = 0; kb < 2; ++kb) {
            uint4 a = ok ? *(const uint4*)(qp + kb * 32) : z4;
            *(uint4*)&qa[kb] = a;
        }
    }
    int jj[7];
    #pragma unroll
    for (int s1 = 0; s1 < 7; ++s1) jj[s1] = (nh * 7 + s1) * 16 + l16;
    half8 kfh[7];
    #pragma unroll
    for (int s1 = 0; s1 < 7; ++s1)
        kfh[s1] = ld_h8(khot + jj[s1] * 32 + quad * 8);

    // K stage: 224 rows x 8 chunks (8 u16); LDS dest linear t*16B
    // (wave-uniform base + lane*16); source col swizzled chunk^(row&7).
    #pragma unroll
    for (int t2 = 0; t2 < 4; ++t2) {
        int t = tid + t2 * 512;
        int row = t >> 3, chunk = t & 7;
        if (t < 1792 && row < 197)
            gload16(kh + base + (size_t)row * 64 + ((chunk ^ (row & 7)) * 8),
                    &Kst[(w * 64 + t2 * 512) * 8]);
    }
    // zero rows 197..223 (27 rows x 8 chunks = 216 x 16B)
    if (tid < 216)
        *(uint4*)&Kst[197 * 64 + tid * 8] = z4;

    // ---- phase 0: Tvh = Q @ rel_k tables (cols nh*32 .. nh*32+31), f16 store
    #pragma unroll
    for (int s2 = 0; s2 < 2; ++s2) {
        int c = (nh * 2 + s2) * 16 + l16;
        f32x4 acc = (f32x4){0, 0, 0, 0};
        #pragma unroll
        for (int kb = 0; kb < 2; ++kb) {
            half8 th = ld_h8(tk + c * 64 + kb * 32 + quad * 8);
            acc = MFMA_H(qa[kb], th, acc, 0, 0, 0);
        }
        #pragma unroll
        for (int r = 0; r < 4; ++r)
            Tvh16[(mr0 + quad * 4 + r) * 68 + c] = f2h(acc[r]);
    }
    __syncthreads();   // Kst (gload drained by barrier) + zeros + Tvh visible

    // ---- build augmented-Q frag from Tvh (row-gathered rel-k bias coeffs)
    half8 qa2;
    {
        int m = mr0 + l16;
        int i = I0 + m;
        u16 vals[8];
        if (i >= 1 && i < 197) {
            int qi = i - 1;
            int iv = qi / 14, ih = qi - iv * 14;
            #pragma unroll
            for (int e = 0; e < 8; ++e) {
                int c = quad * 8 + e;
                u16 v = 0;
                if (c < 14)      v = Tvh16[m * 68 + (c - iv + 15)];
                else if (c < 28) v = Tvh16[m * 68 + 32 + ((c - 14) - ih + 15)];
                vals[e] = v;
            }
        } else {
            #pragma unroll
            for (int e = 0; e < 8; ++e) vals[e] = 0;
        }
        *(uint4*)&qa2 = *(uint4*)vals;
    }

    // ---- phase 1: S = Q.K^T + bias, all MFMA (7 n-frags; 3 kb each;
    //      Kst read with matching XOR swizzle; khot from registers, LAST)
    f32x4 sacc[7];
    #pragma unroll
    for (int s1 = 0; s1 < 7; ++s1) {
        int j = jj[s1];
        f32x4 c = MFMA_H(qa[0], ld_h8(&Kst[j * 64 + ((quad ^ (j & 7)) * 8)]),
                         (f32x4){0, 0, 0, 0}, 0, 0, 0);
        c = MFMA_H(qa[1], ld_h8(&Kst[j * 64 + (((quad + 4) ^ (j & 7)) * 8)]), c, 0, 0, 0);
        c = MFMA_H(qa2, kfh[s1], c, 0, 0, 0);
        sacc[s1] = c;
    }

    // ---- partial row max -> red (scale once after max; padded cols are 0)
    #pragma unroll
    for (int r = 0; r < 4; ++r) {
        float mx = sacc[0][r];
        #pragma unroll
        for (int s1 = 1; s1 < 7; ++s1) mx = fmaxf(mx, sacc[s1][r]);
        mx *= SCALE_;
        #pragma unroll
        for (int off = 1; off < 16; off <<= 1) mx = fmaxf(mx, __shfl_xor(mx, off, 64));
        if (l16 == 0) red[(mr0 + quad * 4 + r) * 4 + nh] = mx;
    }
    __syncthreads();   // red(max) ready; Kst dead beyond this point

    // ---- exp + partial sums + write Ph (unnormalized p), zero cols 208..223
    #pragma unroll
    for (int r = 0; r < 4; ++r) {
        int m = mr0 + quad * 4 + r;
        float M = fmaxf(red[m * 4], red[m * 4 + 1]);
        float sum = 0.f;
        #pragma unroll
        for (int s1 = 0; s1 < 7; ++s1) {
            float pv = (jj[s1] < 197) ? __expf(sacc[s1][r] * SCALE_ - M) : 0.f;
            sacc[s1][r] = pv;
            sum += pv;
        }
        #pragma unroll
        for (int off = 1; off < 16; off <<= 1) sum += __shfl_xor(sum, off, 64);
        if (l16 == 0) red[m * 4 + 2 + nh] = sum;
    }
    #pragma unroll
    for (int s1 = 0; s1 < 7; ++s1) {
        int j = jj[s1];
        if (j < 208) {
            #pragma unroll
            for (int r = 0; r < 4; ++r)
                Ph[(mr0 + quad * 4 + r) * 296 + j] = f2h(sacc[s1][r]);
        }
    }
    #pragma unroll
    for (int t = 0; t < 2; ++t) {
        int ii2 = tid + t * 512;  // 1024 items: rows 0..63, cols 208..223
        Ph[(ii2 >> 4) * 296 + 208 + (ii2 & 15)] = 0;
    }
    __syncthreads();   // p cols 0..223 + sums ready

    // ---- Bs = P @ G^T via MFMA: Bs[m][g], g 0..13 = v-group sums,
    //      g 16..29 = h-group sums. Wave w: rows mr0..mr0+15, cols nh*16..+15.
    {
        f32x4 bacc = (f32x4){0, 0, 0, 0};
        #pragma unroll
        for (int ks = 0; ks < 7; ++ks) {
            half8 ap = ld_h8(&Ph[(mr0 + l16) * 296 + ks * 32 + quad * 8]);
            half8 gp = ld_h8(gt + (nh * 16 + l16) * 224 + ks * 32 + quad * 8);
            bacc = MFMA_H(ap, gp, bacc, 0, 0, 0);
        }
        #pragma unroll
        for (int r = 0; r < 4; ++r)
            BsT[(mr0 + quad * 4 + r) * 36 + nh * 16 + l16] = bacc[r];
    }
    // zero pad cols 272..287 while Bs lands
    for (int t = tid; t < 64 * 16; t += 512)
        Ph[(t >> 4) * 296 + 272 + (t & 15)] = 0;
    __syncthreads();   // Bs ready

    // ---- parallel scatter: Ph cols 208..271 (shifted histogram placement)
    #pragma unroll
    for (int t = 0; t < 8; ++t) {
        int idx = tid + t * 512;       // 4096 = 64 rows x 64 cols
        int m = idx >> 6, c = idx & 63;
        int i = I0 + m;
        float val;
        if (i == 0) {
            val = (c == 0 || c == 32) ? (red[m * 4 + 2] + red[m * 4 + 3]) : 0.f;
        } else {
            int qi = i - 1;
            int iv = qi / 14, ih = qi - (qi / 14) * 14;
            int r = c & 31;
            int bidx = r + ((c < 32) ? iv : ih) - 15;
            bool ok = (bidx >= 0) && (bidx <= 13) && (r < 30);
            int src = ((c < 32) ? 0 : 16) + min(13, max(0, bidx));
            val = ok ? BsT[m * 36 + src] : 0.f;
            if (r == 0) val += h2f(Ph[m * 296]);
        }
        Ph[m * 296 + 208 + c] = f2h(val);
    }
    __syncthreads();   // Ph complete

    // ---- phase 2: O = Ph @ vt^T (K=288), B-frags from global
    {
        f32x4 oacc[2] = {(f32x4){0, 0, 0, 0}, (f32x4){0, 0, 0, 0}};
        const u16* vb = vt + (size_t)bh * 64 * 288;
        #pragma unroll
        for (int ks = 0; ks < 9; ++ks) {
            half8 ap = ld_h8(&Ph[(mr0 + l16) * 296 + ks * 32 + quad * 8]);
            #pragma unroll
            for (int sd = 0; sd < 2; ++sd) {
                int d = (nh * 2 + sd) * 16 + l16;
                half8 bv = ld_h8(vb + (size_t)d * 288 + ks * 32 + quad * 8);
                oacc[sd] = MFMA_H(ap, bv, oacc[sd], 0, 0, 0);
            }
        }
        int b = bh / 12, h = bh - b * 12;
        float rl[4];
        #pragma unroll
        for (int r = 0; r < 4; ++r) {
            int m = mr0 + quad * 4 + r;
            rl[r] = 1.f / (red[m * 4 + 2] + red[m * 4 + 3]);
        }
        #pragma unroll
        for (int sd = 0; sd < 2; ++sd) {
            int d = (nh * 2 + sd) * 16 + l16;
            #pragma unroll
            for (int r = 0; r < 4; ++r) {
                int i = I0 + mr0 + quad * 4 + r;
                if (i < 197) {
                    oh[((size_t)(b * 197 + i)) * 768 + h * 64 + d] =
                        f2h(oacc[sd][r] * rl[r]);
                }
            }
        }
    }
}

// ---------------------------------------------------------------------------
extern "C" void kernel_launch(void* const* d_in, const int* in_sizes, int n_in,
                              void* d_out, int out_size, void* d_ws, size_t ws_size,
                              hipStream_t stream)
{
    const float* x   = (const float*)d_in[0];
    const float* wq  = (const float*)d_in[1];
    const float* bq  = (const float*)d_in[2];
    const float* wk  = (const float*)d_in[3];
    const float* bk  = (const float*)d_in[4];
    const float* wv  = (const float*)d_in[5];
    const float* bv  = (const float*)d_in[6];
    const float* wp  = (const float*)d_in[7];
    const float* bp  = (const float*)d_in[8];
    const float* rkv = (const float*)d_in[9];
    const float* rkh = (const float*)d_in[10];
    const float* rvv = (const float*)d_in[11];
    const float* rvh = (const float*)d_in[12];
    float* out = (float*)d_out;

    const size_t SZX = (size_t)12608 * 768;
    const size_t SZW = (size_t)768 * 768;
    const size_t SZVT = (size_t)768 * 64 * 288;

    u16* xh  = (u16*)d_ws;
    u16* qh_ = xh + SZX;
    u16* kh_ = qh_ + SZX;
    u16* vt  = kh_ + SZX;
    u16* wt  = vt + SZVT;
    u16* wqh = wt;
    u16* wkh = wt + SZW;
    u16* wvh = wt + 2 * SZW;
    u16* wph = wt + 3 * SZW;
    u16* tk  = wt + 4 * SZW;
    u16* gt  = tk + 4096;
    u16* khot = gt + 32 * 224;
    u16* oh_ = xh;   // overlay: x dead after QKV projection

    // all preps fused: 4728 + 576 + 16 + 28 + 28 + 768 = 6144 blocks
    prep_all<<<6144, 256, 0, stream>>>(
        x, wq, wk, wv, wp, rkv, rkh, rvv, rvh,
        xh, wqh, wkh, wvh, wph, tk, gt, khot, vt);

    // QKV: 8 XCDs * 13 m-slots * (6n * 3z) = 1872 blocks; V lands in vt
    gemm_f16<<<1872, 256, 0, stream>>>(
        xh, wqh, wkh, wvh, bq, bk, bv, qh_, kh_, vt, nullptr, 3, 0);

    attn_mfma<<<3072, 512, 0, stream>>>(qh_, kh_, tk, vt, gt, khot, oh_);

    // proj: 8 * 13 * 6 = 624 blocks
    gemm_f16<<<624, 256, 0, stream>>>(
        oh_, wph, wph, wph, bp, bp, bp, nullptr, nullptr, nullptr, out, 1, 1);
}

// Round 9
// 300.039 us; speedup vs baseline: 1.1662x; 1.1662x over previous
//
#include <hip/hip_runtime.h>
#include <math.h>

#define SCALE_ 0.125f

typedef unsigned short u16;
typedef __attribute__((ext_vector_type(8))) _Float16 half8;
typedef __attribute__((ext_vector_type(4))) float f32x4;
#define MFMA_H __builtin_amdgcn_mfma_f32_16x16x32_f16

__device__ __forceinline__ u16 f2h(float f) {
    union { _Float16 h; u16 u; } v; v.h = (_Float16)f; return v.u;
}
__device__ __forceinline__ float h2f(u16 u) {
    union { _Float16 h; u16 u; } v; v.u = u; return (float)v.h;
}
__device__ __forceinline__ void gload16(const u16* g, u16* l) {
    __builtin_amdgcn_global_load_lds(
        (const __attribute__((address_space(1))) void*)g,
        (__attribute__((address_space(3))) void*)l, 16, 0, 0);
}
__device__ __forceinline__ half8 ld_h8(const u16* p) {
    return *(const half8*)p;
}

// ---------------------------------------------------------------------------
// prep_all: all input-prep fused into one grid-sectioned kernel.
//   sect A [0,4728)      : x -> f16
//   sect B [4728,5304)   : transpose weights Wt[n][k] f16 (4 weights x 12x12)
//   sect C1 [5304,5320)  : tk[r][d] f16 (rel_k tables, padded rows)
//   sect C2 [5320,5348)  : gt[g][j] 32x224 indicator (value-bias histogram)
//   sect C3 [5348,5376)  : khot[j][c] 224x32 one-hot (key-bias K-augment)
//   sect D [5376,6144)   : vt const cols 197..287 per bh
// ---------------------------------------------------------------------------
__global__ void prep_all(const float* __restrict__ x,
                         const float* __restrict__ w0, const float* __restrict__ w1,
                         const float* __restrict__ w2, const float* __restrict__ w3,
                         const float* __restrict__ rkv, const float* __restrict__ rkh,
                         const float* __restrict__ rvv, const float* __restrict__ rvh,
                         u16* __restrict__ xh,
                         u16* o0, u16* o1, u16* o2, u16* o3,
                         u16* __restrict__ tk, u16* __restrict__ gt,
                         u16* __restrict__ khot, u16* __restrict__ vtp) {
    __shared__ float t[64 * 68];
    int b = blockIdx.x;
    const int tid = threadIdx.x;

    if (b < 4728) {                       // ---- sect A: x -> f16
        size_t idx = ((size_t)b * 256 + tid) * 8;
        float4 a = *(const float4*)(x + idx), bb = *(const float4*)(x + idx + 4);
        float f[8] = {a.x, a.y, a.z, a.w, bb.x, bb.y, bb.z, bb.w};
        u16 hs[8];
        #pragma unroll
        for (int e = 0; e < 8; ++e) hs[e] = f2h(f[e]);
        *(uint4*)(xh + idx) = *(uint4*)hs;
        return;
    }
    b -= 4728;
    if (b < 576) {                        // ---- sect B: weight transpose
        int z = b / 144, rem = b - z * 144;
        int by = rem / 12, bx = rem - by * 12;
        const float* W; u16* oh;
        if (z == 0)      { W = w0; oh = o0; }
        else if (z == 1) { W = w1; oh = o1; }
        else if (z == 2) { W = w2; oh = o2; }
        else             { W = w3; oh = o3; }
        int k0 = by * 64, n0 = bx * 64;
        #pragma unroll
        for (int rr = 0; rr < 4; ++rr) {
            int r = (tid >> 4) + rr * 16;
            int c = (tid & 15) * 4;
            *(float4*)&t[r * 68 + c] = *(const float4*)(W + (size_t)(k0 + r) * 768 + n0 + c);
        }
        __syncthreads();
        int n = tid >> 2, kc = (tid & 3) * 16;
        u16 hs[16];
        #pragma unroll
        for (int e = 0; e < 16; ++e) hs[e] = f2h(t[(kc + e) * 68 + n]);
        size_t o = (size_t)(n0 + n) * 768 + k0 + kc;
        *(uint4*)(oh + o) = *(uint4*)hs;
        *(uint4*)(oh + o + 8) = *(uint4*)(hs + 8);
        return;
    }
    b -= 576;
    if (b < 16) {                         // ---- sect C1: tk
        int idx = b * 256 + tid;          // 0..4095
        int r = idx >> 6, d = idx & 63;
        float tv = 0.f;
        if (r < 30) tv = rkv[r * 64 + d];
        else if (r >= 32 && r < 62) tv = rkh[(r - 32) * 64 + d];
        tk[idx] = f2h(tv);
        return;
    }
    b -= 16;
    if (b < 28) {                         // ---- sect C2: gt
        int idx = b * 256 + tid;          // 0..7167
        int g = idx / 224, j = idx - (idx / 224) * 224;
        float v = 0.f;
        if (j >= 1 && j < 197) {
            int jq = j - 1;
            int jv = jq / 14, jh = jq - jv * 14;
            if (g < 14) v = (jv == g) ? 1.f : 0.f;
            else if (g >= 16 && g < 30) v = (jh == g - 16) ? 1.f : 0.f;
        }
        gt[idx] = f2h(v);
        return;
    }
    b -= 28;
    if (b < 28) {                         // ---- sect C3: khot
        int idx = b * 256 + tid;          // 0..7167
        int j = idx >> 5, c = idx & 31;
        float v = 0.f;
        if (j >= 1 && j < 197) {
            int jq = j - 1;
            int jv = jq / 14, jh = jq - jv * 14;
            if (c < 14) v = (jv == c) ? 1.f : 0.f;
            else if (c < 28) v = (jh == c - 14) ? 1.f : 0.f;
        }
        khot[idx] = f2h(v);
        return;
    }
    b -= 28;
    {                                     // ---- sect D: vt const part, bh = b
        u16* vb = vtp + (size_t)b * 64 * 288;
        for (int tt = tid; tt < 64 * 91; tt += 256) {
            int d = tt / 91;
            int c = 197 + (tt - d * 91);
            u16 val = 0;
            if (c >= 208 && c < 272) {
                int rr = c - 208;
                float v = 0.f;
                if (rr < 30) v = rvv[rr * 64 + d];
                else if (rr >= 32 && rr < 62) v = rvh[(rr - 32) * 64 + d];
                val = f2h(v);
            }
            vb[d * 288 + c] = val;
        }
    }
}

// ---------------------------------------------------------------------------
// Single-pass f16 MFMA GEMM, XCD-grouped work mapping, BK=64, LDS-bounce
// epilogue. C(12608,768) = A @ B + bias; A f16 row-major, B as Bt[n][k] f16.
// kind 0: z=0/1 -> q/k row-major scatter; z=2 -> V written TRANSPOSED into
// vt[bh][d][288] via a TRANSPOSED LDS bounce Ct[col][key] (stride 134 u16,
// <=2-way banks) so the global store has lane=key -> 128B coalesced runs.
// R8 lesson: per-lane-rotated d made the global store a 64-way scatter
// (QKV gemm 60->117us); layout must keep lane-contiguity on the HBM side.
// kind 1: plain fp32 output.
// ---------------------------------------------------------------------------
__global__ __launch_bounds__(256, 4) void gemm_f16(
    const u16* __restrict__ Ah,
    const u16* __restrict__ B0, const u16* __restrict__ B1, const u16* __restrict__ B2,
    const float* __restrict__ bias0, const float* __restrict__ bias1,
    const float* __restrict__ bias2,
    u16* qo, u16* ko, u16* vo, float* outf, int nz, int kind)
{
    __shared__ u16 SM[128 * 134 + 1024];   // 17152+1024 u16; staging uses 16384
    u16* As = SM;
    u16* Bs = SM + 128 * 64;

    const int p = blockIdx.x;
    const int xcd = p & 7, s = p >> 3;
    const int mcnt = (xcd < 3) ? 13 : 12;
    const int mbase = (xcd < 3) ? xcd * 13 : 39 + (xcd - 3) * 12;
    const int jn = 6 * nz;
    if (s >= mcnt * jn) return;
    const int mb = mbase + s / jn;
    const int j = s % jn;
    const int z = j / 6;
    const int nb = j % 6;

    const u16* Bt = B0; const float* bias = bias0;
    if (z == 1) { Bt = B1; bias = bias1; }
    else if (z == 2) { Bt = B2; bias = bias2; }

    const int m0 = mb * 128, n0 = nb * 128;
    const int tid = threadIdx.x;
    const int w = tid >> 6, lane = tid & 63, quad = lane >> 4, l16 = lane & 15;
    const int wm = (w >> 1) * 64, wn = (w & 1) * 64;
    const int rl8 = lane >> 3, cs = lane & 7;
    const int csrc = (cs ^ rl8) * 8;

    f32x4 acc[4][4];
    #pragma unroll
    for (int a = 0; a < 4; ++a)
        #pragma unroll
        for (int b = 0; b < 4; ++b) acc[a][b] = (f32x4){0, 0, 0, 0};

    for (int kt = 0; kt < 768; kt += 64) {
        __syncthreads();
        #pragma unroll
        for (int i = 0; i < 4; ++i) {
            int r = w * 32 + i * 8 + rl8;
            int arow = min(m0 + r, 12607);
            gload16(Ah + (size_t)arow * 768 + kt + csrc, &As[(w * 32 + i * 8) * 64]);
            gload16(Bt + (size_t)(n0 + r) * 768 + kt + csrc, &Bs[(w * 32 + i * 8) * 64]);
        }
        __syncthreads();
        #pragma unroll
        for (int kb = 0; kb < 2; ++kb) {
            const int slot = ((kb * 4 + quad) ^ (l16 & 7)) * 8;
            half8 ah[4], bf[4];
            #pragma unroll
            for (int mi = 0; mi < 4; ++mi) {
                ah[mi] = ld_h8(&As[(wm + mi * 16 + l16) * 64 + slot]);
                bf[mi] = ld_h8(&Bs[(wn + mi * 16 + l16) * 64 + slot]);
            }
            #pragma unroll
            for (int ni = 0; ni < 4; ++ni)
                #pragma unroll
                for (int mi = 0; mi < 4; ++mi)
                    acc[mi][ni] = MFMA_H(ah[mi], bf[ni], acc[mi][ni], 0, 0, 0);
        }
    }

    if (kind == 1) {
        #pragma unroll
        for (int mi = 0; mi < 4; ++mi) {
            #pragma unroll
            for (int r = 0; r < 4; ++r) {
                int gr = m0 + wm + mi * 16 + quad * 4 + r;
                if (gr >= 12608) continue;
                #pragma unroll
                for (int ni = 0; ni < 4; ++ni) {
                    int gc = n0 + wn + ni * 16 + l16;
                    outf[(size_t)gr * 768 + gc] = acc[mi][ni][r] + bias[gc];
                }
            }
        }
        return;
    }

    __syncthreads();

    if (z == 2) {
        // ---- transposed LDS bounce: Ct[col*134 + key] then coalesced store
        u16* Ct = SM;
        #pragma unroll
        for (int mi = 0; mi < 4; ++mi) {
            #pragma unroll
            for (int ni = 0; ni < 4; ++ni) {
                int col = wn + ni * 16 + l16;
                float bv = bias[n0 + col];
                #pragma unroll
                for (int r = 0; r < 4; ++r)
                    Ct[col * 134 + (wm + mi * 16 + quad * 4 + r)] =
                        f2h(acc[mi][ni][r] + bv);
            }
        }
        __syncthreads();
        // thread = (k2 = key in tile, chalf = head half); loop over d.
        // For fixed d: lanes write 64 consecutive u16 = 128B contiguous.
        int k2 = tid & 127, chalf = tid >> 7;
        int gr = m0 + k2;
        if (gr < 12608) {
            int bb = gr / 197, ii = gr - bb * 197;
            int h = (n0 >> 6) + chalf;
            u16* vbase = vo + ((size_t)(bb * 12 + h) * 64) * 288 + ii;
            #pragma unroll
            for (int dd = 0; dd < 64; ++dd)
                vbase[(size_t)dd * 288] = Ct[(chalf * 64 + dd) * 134 + k2];
        }
        return;
    }

    // ---- q/k: row-major LDS bounce Cs[128][128]
    u16* Cs = SM;
    #pragma unroll
    for (int mi = 0; mi < 4; ++mi) {
        #pragma unroll
        for (int ni = 0; ni < 4; ++ni) {
            int col = wn + ni * 16 + l16;
            float bv = bias[n0 + col];
            #pragma unroll
            for (int r = 0; r < 4; ++r)
                Cs[(wm + mi * 16 + quad * 4 + r) * 128 + col] = f2h(acc[mi][ni][r] + bv);
        }
    }
    __syncthreads();
    u16* O = (z == 0) ? qo : ko;
    int row = tid >> 1, halfc = tid & 1;
    int gr = m0 + row;
    if (gr < 12608) {
        int bb = gr / 197, ii = gr - bb * 197;
        int h = (n0 >> 6) + halfc;
        u16* dst = O + ((size_t)(bb * 12 + h) * 197 + ii) * 64;
        const u16* src = &Cs[row * 128 + halfc * 64];
        #pragma unroll
        for (int e = 0; e < 8; ++e)
            *(uint4*)(dst + e * 8) = *(const uint4*)(src + e * 8);
    }
}

// ---------------------------------------------------------------------------
// Fused attention, single-pass f16 MFMA, register-resident scores.
// XCD-grouped: 4 qt-blocks of one bh run adjacent on one XCD.
// K staged to LDS via global_load_lds DIRECT (zero staging VGPRs): LDS is
// linear [224][64], bank-freedom recovered by pre-swizzling the SOURCE col
// (chunk ^ (row&7)) and reading with the same XOR.
// iRPE key bias via K-augmentation (khot one-hot MFMA), khot register-
// prefetched (R5 lesson). launch_bounds 2nd arg = min BLOCKS/CU here.
// ---------------------------------------------------------------------------
__global__ __launch_bounds__(512, 3) void attn_mfma(
    const u16* __restrict__ qh, const u16* __restrict__ kh,
    const u16* __restrict__ tk, const u16* __restrict__ vt,
    const u16* __restrict__ gt, const u16* __restrict__ khot,
    u16* __restrict__ oh)
{
    __shared__ u16 Ph[64 * 296];      // 37888 B; first used as Kst[224][64] = 28672 B
    __shared__ float BsT[64 * 36];    // 9216 B: phase A = Tvh f16; phase B = Bs f32
    __shared__ float red[64 * 4];     // [m][max0,max1,sum0,sum1]
    u16* Tvh16 = (u16*)BsT;           // 64*68 u16 = 8704 B
    u16* Kst = Ph;                    // overlay: K staging, dead before first Ph write

    const int p = blockIdx.x;
    const int xcd = p & 7, s = p >> 3;
    const int bh = xcd * 96 + (s >> 2);
    const int qt = s & 3;
    const int I0 = qt * 64;
    const int tid = threadIdx.x;
    const int w = tid >> 6, lane = tid & 63, quad = lane >> 4, l16 = lane & 15;
    const int mf = w >> 1, nh = w & 1;
    const int mr0 = mf * 16;
    const size_t base = (size_t)bh * 197 * 64;
    const uint4 z4 = make_uint4(0, 0, 0, 0);

    // ---- issue Q A-frag loads + khot prefetch + K->LDS gload (independent,
    //      in flight under phase 0's MFMAs)
    half8 qa[2];
    {
        int i = I0 + mr0 + l16;
        bool ok = i < 197;
        const u16* qp = qh + base + (size_t)i * 64 + quad * 8;
        #pragma unroll
        for (int kb = 0; kb < 2; ++kb) {
            uint4 a = ok ? *(const uint4*)(qp + kb * 32) : z4;
            *(uint4*)&qa[kb] = a;
        }
    }
    int jj[7];
    #pragma unroll
    for (int s1 = 0; s1 < 7; ++s1) jj[s1] = (nh * 7 + s1) * 16 + l16;
    half8 kfh[7];
    #pragma unroll
    for (int s1 = 0; s1 < 7; ++s1)
        kfh[s1] = ld_h8(khot + jj[s1] * 32 + quad * 8);

    // K stage: 224 rows x 8 chunks (8 u16); LDS dest linear t*16B
    // (wave-uniform base + lane*16); source col swizzled chunk^(row&7).
    #pragma unroll
    for (int t2 = 0; t2 < 4; ++t2) {
        int t = tid + t2 * 512;
        int row = t >> 3, chunk = t & 7;
        if (t < 1792 && row < 197)
            gload16(kh + base + (size_t)row * 64 + ((chunk ^ (row & 7)) * 8),
                    &Kst[(w * 64 + t2 * 512) * 8]);
    }
    // zero rows 197..223 (27 rows x 8 chunks = 216 x 16B)
    if (tid < 216)
        *(uint4*)&Kst[197 * 64 + tid * 8] = z4;

    // ---- phase 0: Tvh = Q @ rel_k tables (cols nh*32 .. nh*32+31), f16 store
    #pragma unroll
    for (int s2 = 0; s2 < 2; ++s2) {
        int c = (nh * 2 + s2) * 16 + l16;
        f32x4 acc = (f32x4){0, 0, 0, 0};
        #pragma unroll
        for (int kb = 0; kb < 2; ++kb) {
            half8 th = ld_h8(tk + c * 64 + kb * 32 + quad * 8);
            acc = MFMA_H(qa[kb], th, acc, 0, 0, 0);
        }
        #pragma unroll
        for (int r = 0; r < 4; ++r)
            Tvh16[(mr0 + quad * 4 + r) * 68 + c] = f2h(acc[r]);
    }
    __syncthreads();   // Kst (gload drained by barrier) + zeros + Tvh visible

    // ---- build augmented-Q frag from Tvh (row-gathered rel-k bias coeffs)
    half8 qa2;
    {
        int m = mr0 + l16;
        int i = I0 + m;
        u16 vals[8];
        if (i >= 1 && i < 197) {
            int qi = i - 1;
            int iv = qi / 14, ih = qi - iv * 14;
            #pragma unroll
            for (int e = 0; e < 8; ++e) {
                int c = quad * 8 + e;
                u16 v = 0;
                if (c < 14)      v = Tvh16[m * 68 + (c - iv + 15)];
                else if (c < 28) v = Tvh16[m * 68 + 32 + ((c - 14) - ih + 15)];
                vals[e] = v;
            }
        } else {
            #pragma unroll
            for (int e = 0; e < 8; ++e) vals[e] = 0;
        }
        *(uint4*)&qa2 = *(uint4*)vals;
    }

    // ---- phase 1: S = Q.K^T + bias, all MFMA (7 n-frags; 3 kb each;
    //      Kst read with matching XOR swizzle; khot from registers, LAST)
    f32x4 sacc[7];
    #pragma unroll
    for (int s1 = 0; s1 < 7; ++s1) {
        int j = jj[s1];
        f32x4 c = MFMA_H(qa[0], ld_h8(&Kst[j * 64 + ((quad ^ (j & 7)) * 8)]),
                         (f32x4){0, 0, 0, 0}, 0, 0, 0);
        c = MFMA_H(qa[1], ld_h8(&Kst[j * 64 + (((quad + 4) ^ (j & 7)) * 8)]), c, 0, 0, 0);
        c = MFMA_H(qa2, kfh[s1], c, 0, 0, 0);
        sacc[s1] = c;
    }

    // ---- partial row max -> red (scale once after max; padded cols are 0)
    #pragma unroll
    for (int r = 0; r < 4; ++r) {
        float mx = sacc[0][r];
        #pragma unroll
        for (int s1 = 1; s1 < 7; ++s1) mx = fmaxf(mx, sacc[s1][r]);
        mx *= SCALE_;
        #pragma unroll
        for (int off = 1; off < 16; off <<= 1) mx = fmaxf(mx, __shfl_xor(mx, off, 64));
        if (l16 == 0) red[(mr0 + quad * 4 + r) * 4 + nh] = mx;
    }
    __syncthreads();   // red(max) ready; Kst dead beyond this point

    // ---- exp + partial sums + write Ph (unnormalized p), zero cols 208..223
    #pragma unroll
    for (int r = 0; r < 4; ++r) {
        int m = mr0 + quad * 4 + r;
        float M = fmaxf(red[m * 4], red[m * 4 + 1]);
        float sum = 0.f;
        #pragma unroll
        for (int s1 = 0; s1 < 7; ++s1) {
            float pv = (jj[s1] < 197) ? __expf(sacc[s1][r] * SCALE_ - M) : 0.f;
            sacc[s1][r] = pv;
            sum += pv;
        }
        #pragma unroll
        for (int off = 1; off < 16; off <<= 1) sum += __shfl_xor(sum, off, 64);
        if (l16 == 0) red[m * 4 + 2 + nh] = sum;
    }
    #pragma unroll
    for (int s1 = 0; s1 < 7; ++s1) {
        int j = jj[s1];
        if (j < 208) {
            #pragma unroll
            for (int r = 0; r < 4; ++r)
                Ph[(mr0 + quad * 4 + r) * 296 + j] = f2h(sacc[s1][r]);
        }
    }
    #pragma unroll
    for (int t = 0; t < 2; ++t) {
        int ii2 = tid + t * 512;  // 1024 items: rows 0..63, cols 208..223
        Ph[(ii2 >> 4) * 296 + 208 + (ii2 & 15)] = 0;
    }
    __syncthreads();   // p cols 0..223 + sums ready

    // ---- Bs = P @ G^T via MFMA: Bs[m][g], g 0..13 = v-group sums,
    //      g 16..29 = h-group sums. Wave w: rows mr0..mr0+15, cols nh*16..+15.
    {
        f32x4 bacc = (f32x4){0, 0, 0, 0};
        #pragma unroll
        for (int ks = 0; ks < 7; ++ks) {
            half8 ap = ld_h8(&Ph[(mr0 + l16) * 296 + ks * 32 + quad * 8]);
            half8 gp = ld_h8(gt + (nh * 16 + l16) * 224 + ks * 32 + quad * 8);
            bacc = MFMA_H(ap, gp, bacc, 0, 0, 0);
        }
        #pragma unroll
        for (int r = 0; r < 4; ++r)
            BsT[(mr0 + quad * 4 + r) * 36 + nh * 16 + l16] = bacc[r];
    }
    // zero pad cols 272..287 while Bs lands
    for (int t = tid; t < 64 * 16; t += 512)
        Ph[(t >> 4) * 296 + 272 + (t & 15)] = 0;
    __syncthreads();   // Bs ready

    // ---- parallel scatter: Ph cols 208..271 (shifted histogram placement)
    #pragma unroll
    for (int t = 0; t < 8; ++t) {
        int idx = tid + t * 512;       // 4096 = 64 rows x 64 cols
        int m = idx >> 6, c = idx & 63;
        int i = I0 + m;
        float val;
        if (i == 0) {
            val = (c == 0 || c == 32) ? (red[m * 4 + 2] + red[m * 4 + 3]) : 0.f;
        } else {
            int qi = i - 1;
            int iv = qi / 14, ih = qi - (qi / 14) * 14;
            int r = c & 31;
            int bidx = r + ((c < 32) ? iv : ih) - 15;
            bool ok = (bidx >= 0) && (bidx <= 13) && (r < 30);
            int src = ((c < 32) ? 0 : 16) + min(13, max(0, bidx));
            val = ok ? BsT[m * 36 + src] : 0.f;
            if (r == 0) val += h2f(Ph[m * 296]);
        }
        Ph[m * 296 + 208 + c] = f2h(val);
    }
    __syncthreads();   // Ph complete

    // ---- phase 2: O = Ph @ vt^T (K=288), B-frags from global
    {
        f32x4 oacc[2] = {(f32x4){0, 0, 0, 0}, (f32x4){0, 0, 0, 0}};
        const u16* vb = vt + (size_t)bh * 64 * 288;
        #pragma unroll
        for (int ks = 0; ks < 9; ++ks) {
            half8 ap = ld_h8(&Ph[(mr0 + l16) * 296 + ks * 32 + quad * 8]);
            #pragma unroll
            for (int sd = 0; sd < 2; ++sd) {
                int d = (nh * 2 + sd) * 16 + l16;
                half8 bv = ld_h8(vb + (size_t)d * 288 + ks * 32 + quad * 8);
                oacc[sd] = MFMA_H(ap, bv, oacc[sd], 0, 0, 0);
            }
        }
        int b = bh / 12, h = bh - b * 12;
        float rl[4];
        #pragma unroll
        for (int r = 0; r < 4; ++r) {
            int m = mr0 + quad * 4 + r;
            rl[r] = 1.f / (red[m * 4 + 2] + red[m * 4 + 3]);
        }
        #pragma unroll
        for (int sd = 0; sd < 2; ++sd) {
            int d = (nh * 2 + sd) * 16 + l16;
            #pragma unroll
            for (int r = 0; r < 4; ++r) {
                int i = I0 + mr0 + quad * 4 + r;
                if (i < 197) {
                    oh[((size_t)(b * 197 + i)) * 768 + h * 64 + d] =
                        f2h(oacc[sd][r] * rl[r]);
                }
            }
        }
    }
}

// ---------------------------------------------------------------------------
extern "C" void kernel_launch(void* const* d_in, const int* in_sizes, int n_in,
                              void* d_out, int out_size, void* d_ws, size_t ws_size,
                              hipStream_t stream)
{
    const float* x   = (const float*)d_in[0];
    const float* wq  = (const float*)d_in[1];
    const float* bq  = (const float*)d_in[2];
    const float* wk  = (const float*)d_in[3];
    const float* bk  = (const float*)d_in[4];
    const float* wv  = (const float*)d_in[5];
    const float* bv  = (const float*)d_in[6];
    const float* wp  = (const float*)d_in[7];
    const float* bp  = (const float*)d_in[8];
    const float* rkv = (const float*)d_in[9];
    const float* rkh = (const float*)d_in[10];
    const float* rvv = (const float*)d_in[11];
    const float* rvh = (const float*)d_in[12];
    float* out = (float*)d_out;

    const size_t SZX = (size_t)12608 * 768;
    const size_t SZW = (size_t)768 * 768;
    const size_t SZVT = (size_t)768 * 64 * 288;

    u16* xh  = (u16*)d_ws;
    u16* qh_ = xh + SZX;
    u16* kh_ = qh_ + SZX;
    u16* vt  = kh_ + SZX;
    u16* wt  = vt + SZVT;
    u16* wqh = wt;
    u16* wkh = wt + SZW;
    u16* wvh = wt + 2 * SZW;
    u16* wph = wt + 3 * SZW;
    u16* tk  = wt + 4 * SZW;
    u16* gt  = tk + 4096;
    u16* khot = gt + 32 * 224;
    u16* oh_ = xh;   // overlay: x dead after QKV projection

    // all preps fused: 4728 + 576 + 16 + 28 + 28 + 768 = 6144 blocks
    prep_all<<<6144, 256, 0, stream>>>(
        x, wq, wk, wv, wp, rkv, rkh, rvv, rvh,
        xh, wqh, wkh, wvh, wph, tk, gt, khot, vt);

    // QKV: 8 XCDs * 13 m-slots * (6n * 3z) = 1872 blocks; V lands in vt
    gemm_f16<<<1872, 256, 0, stream>>>(
        xh, wqh, wkh, wvh, bq, bk, bv, qh_, kh_, vt, nullptr, 3, 0);

    attn_mfma<<<3072, 512, 0, stream>>>(qh_, kh_, tk, vt, gt, khot, oh_);

    // proj: 8 * 13 * 6 = 624 blocks
    gemm_f16<<<624, 256, 0, stream>>>(
        oh_, wph, wph, wph, bp, bp, bp, nullptr, nullptr, nullptr, out, 1, 1);
}

// Round 10
// 285.396 us; speedup vs baseline: 1.2261x; 1.0513x over previous
//
#include <hip/hip_runtime.h>
#include <math.h>

#define SCALE_ 0.125f

typedef unsigned short u16;
typedef __attribute__((ext_vector_type(8))) _Float16 half8;
typedef __attribute__((ext_vector_type(4))) float f32x4;
#define MFMA_H __builtin_amdgcn_mfma_f32_16x16x32_f16

__device__ __forceinline__ u16 f2h(float f) {
    union { _Float16 h; u16 u; } v; v.h = (_Float16)f; return v.u;
}
__device__ __forceinline__ float h2f(u16 u) {
    union { _Float16 h; u16 u; } v; v.u = u; return (float)v.h;
}
__device__ __forceinline__ void gload16(const u16* g, u16* l) {
    __builtin_amdgcn_global_load_lds(
        (const __attribute__((address_space(1))) void*)g,
        (__attribute__((address_space(3))) void*)l, 16, 0, 0);
}
__device__ __forceinline__ half8 ld_h8(const u16* p) {
    return *(const half8*)p;
}

// ---------------------------------------------------------------------------
// prep_all: all input-prep fused into one grid-sectioned kernel.
//   sect A [0,4728)      : x -> f16
//   sect B [4728,5304)   : transpose weights Wt[n][k] f16 (4 weights x 12x12)
//   sect C1 [5304,5320)  : tk[r][d] f16 (rel_k tables, padded rows)
//   sect C2 [5320,5348)  : gt[g][j] 32x224 indicator (value-bias histogram)
//   sect C3 [5348,5376)  : khot[j][c] 224x32 one-hot (key-bias K-augment)
//   sect D [5376,6144)   : vt const cols 197..287 per bh
// ---------------------------------------------------------------------------
__global__ void prep_all(const float* __restrict__ x,
                         const float* __restrict__ w0, const float* __restrict__ w1,
                         const float* __restrict__ w2, const float* __restrict__ w3,
                         const float* __restrict__ rkv, const float* __restrict__ rkh,
                         const float* __restrict__ rvv, const float* __restrict__ rvh,
                         u16* __restrict__ xh,
                         u16* o0, u16* o1, u16* o2, u16* o3,
                         u16* __restrict__ tk, u16* __restrict__ gt,
                         u16* __restrict__ khot, u16* __restrict__ vtp) {
    __shared__ float t[64 * 68];
    int b = blockIdx.x;
    const int tid = threadIdx.x;

    if (b < 4728) {                       // ---- sect A: x -> f16
        size_t idx = ((size_t)b * 256 + tid) * 8;
        float4 a = *(const float4*)(x + idx), bb = *(const float4*)(x + idx + 4);
        float f[8] = {a.x, a.y, a.z, a.w, bb.x, bb.y, bb.z, bb.w};
        u16 hs[8];
        #pragma unroll
        for (int e = 0; e < 8; ++e) hs[e] = f2h(f[e]);
        *(uint4*)(xh + idx) = *(uint4*)hs;
        return;
    }
    b -= 4728;
    if (b < 576) {                        // ---- sect B: weight transpose
        int z = b / 144, rem = b - z * 144;
        int by = rem / 12, bx = rem - by * 12;
        const float* W; u16* oh;
        if (z == 0)      { W = w0; oh = o0; }
        else if (z == 1) { W = w1; oh = o1; }
        else if (z == 2) { W = w2; oh = o2; }
        else             { W = w3; oh = o3; }
        int k0 = by * 64, n0 = bx * 64;
        #pragma unroll
        for (int rr = 0; rr < 4; ++rr) {
            int r = (tid >> 4) + rr * 16;
            int c = (tid & 15) * 4;
            *(float4*)&t[r * 68 + c] = *(const float4*)(W + (size_t)(k0 + r) * 768 + n0 + c);
        }
        __syncthreads();
        int n = tid >> 2, kc = (tid & 3) * 16;
        u16 hs[16];
        #pragma unroll
        for (int e = 0; e < 16; ++e) hs[e] = f2h(t[(kc + e) * 68 + n]);
        size_t o = (size_t)(n0 + n) * 768 + k0 + kc;
        *(uint4*)(oh + o) = *(uint4*)hs;
        *(uint4*)(oh + o + 8) = *(uint4*)(hs + 8);
        return;
    }
    b -= 576;
    if (b < 16) {                         // ---- sect C1: tk
        int idx = b * 256 + tid;          // 0..4095
        int r = idx >> 6, d = idx & 63;
        float tv = 0.f;
        if (r < 30) tv = rkv[r * 64 + d];
        else if (r >= 32 && r < 62) tv = rkh[(r - 32) * 64 + d];
        tk[idx] = f2h(tv);
        return;
    }
    b -= 16;
    if (b < 28) {                         // ---- sect C2: gt
        int idx = b * 256 + tid;          // 0..7167
        int g = idx / 224, j = idx - (idx / 224) * 224;
        float v = 0.f;
        if (j >= 1 && j < 197) {
            int jq = j - 1;
            int jv = jq / 14, jh = jq - jv * 14;
            if (g < 14) v = (jv == g) ? 1.f : 0.f;
            else if (g >= 16 && g < 30) v = (jh == g - 16) ? 1.f : 0.f;
        }
        gt[idx] = f2h(v);
        return;
    }
    b -= 28;
    if (b < 28) {                         // ---- sect C3: khot
        int idx = b * 256 + tid;          // 0..7167
        int j = idx >> 5, c = idx & 31;
        float v = 0.f;
        if (j >= 1 && j < 197) {
            int jq = j - 1;
            int jv = jq / 14, jh = jq - jv * 14;
            if (c < 14) v = (jv == c) ? 1.f : 0.f;
            else if (c < 28) v = (jh == c - 14) ? 1.f : 0.f;
        }
        khot[idx] = f2h(v);
        return;
    }
    b -= 28;
    {                                     // ---- sect D: vt const part, bh = b
        u16* vb = vtp + (size_t)b * 64 * 288;
        for (int tt = tid; tt < 64 * 91; tt += 256) {
            int d = tt / 91;
            int c = 197 + (tt - d * 91);
            u16 val = 0;
            if (c >= 208 && c < 272) {
                int rr = c - 208;
                float v = 0.f;
                if (rr < 30) v = rvv[rr * 64 + d];
                else if (rr >= 32 && rr < 62) v = rvh[(rr - 32) * 64 + d];
                val = f2h(v);
            }
            vb[d * 288 + c] = val;
        }
    }
}

// ---------------------------------------------------------------------------
// Single-pass f16 MFMA GEMM, XCD-grouped work mapping, BK=64, LDS-bounce
// epilogue. C(12608,768) = A @ B + bias; A f16 row-major, B as Bt[n][k] f16.
// kind 0: z=0/1 -> q/k row-major scatter; z=2 -> V written TRANSPOSED into
// vt[bh][d][288] via a TRANSPOSED LDS bounce Ct[col][key] (stride 134 u16,
// <=2-way banks) so the global store has lane=key -> 128B coalesced runs.
// R8 lesson: per-lane-rotated d made the global store a 64-way scatter
// (QKV gemm 60->117us); layout must keep lane-contiguity on the HBM side.
// kind 1: plain fp32 output.
// ---------------------------------------------------------------------------
__global__ __launch_bounds__(256, 4) void gemm_f16(
    const u16* __restrict__ Ah,
    const u16* __restrict__ B0, const u16* __restrict__ B1, const u16* __restrict__ B2,
    const float* __restrict__ bias0, const float* __restrict__ bias1,
    const float* __restrict__ bias2,
    u16* qo, u16* ko, u16* vo, float* outf, int nz, int kind)
{
    __shared__ u16 SM[128 * 134 + 1024];   // 17152+1024 u16; staging uses 16384
    u16* As = SM;
    u16* Bs = SM + 128 * 64;

    const int p = blockIdx.x;
    const int xcd = p & 7, s = p >> 3;
    const int mcnt = (xcd < 3) ? 13 : 12;
    const int mbase = (xcd < 3) ? xcd * 13 : 39 + (xcd - 3) * 12;
    const int jn = 6 * nz;
    if (s >= mcnt * jn) return;
    const int mb = mbase + s / jn;
    const int j = s % jn;
    const int z = j / 6;
    const int nb = j % 6;

    const u16* Bt = B0; const float* bias = bias0;
    if (z == 1) { Bt = B1; bias = bias1; }
    else if (z == 2) { Bt = B2; bias = bias2; }

    const int m0 = mb * 128, n0 = nb * 128;
    const int tid = threadIdx.x;
    const int w = tid >> 6, lane = tid & 63, quad = lane >> 4, l16 = lane & 15;
    const int wm = (w >> 1) * 64, wn = (w & 1) * 64;
    const int rl8 = lane >> 3, cs = lane & 7;
    const int csrc = (cs ^ rl8) * 8;

    f32x4 acc[4][4];
    #pragma unroll
    for (int a = 0; a < 4; ++a)
        #pragma unroll
        for (int b = 0; b < 4; ++b) acc[a][b] = (f32x4){0, 0, 0, 0};

    for (int kt = 0; kt < 768; kt += 64) {
        __syncthreads();
        #pragma unroll
        for (int i = 0; i < 4; ++i) {
            int r = w * 32 + i * 8 + rl8;
            int arow = min(m0 + r, 12607);
            gload16(Ah + (size_t)arow * 768 + kt + csrc, &As[(w * 32 + i * 8) * 64]);
            gload16(Bt + (size_t)(n0 + r) * 768 + kt + csrc, &Bs[(w * 32 + i * 8) * 64]);
        }
        __syncthreads();
        #pragma unroll
        for (int kb = 0; kb < 2; ++kb) {
            const int slot = ((kb * 4 + quad) ^ (l16 & 7)) * 8;
            half8 ah[4], bf[4];
            #pragma unroll
            for (int mi = 0; mi < 4; ++mi) {
                ah[mi] = ld_h8(&As[(wm + mi * 16 + l16) * 64 + slot]);
                bf[mi] = ld_h8(&Bs[(wn + mi * 16 + l16) * 64 + slot]);
            }
            #pragma unroll
            for (int ni = 0; ni < 4; ++ni)
                #pragma unroll
                for (int mi = 0; mi < 4; ++mi)
                    acc[mi][ni] = MFMA_H(ah[mi], bf[ni], acc[mi][ni], 0, 0, 0);
        }
    }

    if (kind == 1) {
        #pragma unroll
        for (int mi = 0; mi < 4; ++mi) {
            #pragma unroll
            for (int r = 0; r < 4; ++r) {
                int gr = m0 + wm + mi * 16 + quad * 4 + r;
                if (gr >= 12608) continue;
                #pragma unroll
                for (int ni = 0; ni < 4; ++ni) {
                    int gc = n0 + wn + ni * 16 + l16;
                    outf[(size_t)gr * 768 + gc] = acc[mi][ni][r] + bias[gc];
                }
            }
        }
        return;
    }

    __syncthreads();

    if (z == 2) {
        // ---- transposed LDS bounce: Ct[col*134 + key] then coalesced store
        u16* Ct = SM;
        #pragma unroll
        for (int mi = 0; mi < 4; ++mi) {
            #pragma unroll
            for (int ni = 0; ni < 4; ++ni) {
                int col = wn + ni * 16 + l16;
                float bv = bias[n0 + col];
                #pragma unroll
                for (int r = 0; r < 4; ++r)
                    Ct[col * 134 + (wm + mi * 16 + quad * 4 + r)] =
                        f2h(acc[mi][ni][r] + bv);
            }
        }
        __syncthreads();
        // thread = (k2 = key in tile, chalf = head half); loop over d.
        // For fixed d: lanes write 64 consecutive u16 = 128B contiguous.
        int k2 = tid & 127, chalf = tid >> 7;
        int gr = m0 + k2;
        if (gr < 12608) {
            int bb = gr / 197, ii = gr - bb * 197;
            int h = (n0 >> 6) + chalf;
            u16* vbase = vo + ((size_t)(bb * 12 + h) * 64) * 288 + ii;
            #pragma unroll
            for (int dd = 0; dd < 64; ++dd)
                vbase[(size_t)dd * 288] = Ct[(chalf * 64 + dd) * 134 + k2];
        }
        return;
    }

    // ---- q/k: row-major LDS bounce Cs[128][128]
    u16* Cs = SM;
    #pragma unroll
    for (int mi = 0; mi < 4; ++mi) {
        #pragma unroll
        for (int ni = 0; ni < 4; ++ni) {
            int col = wn + ni * 16 + l16;
            float bv = bias[n0 + col];
            #pragma unroll
            for (int r = 0; r < 4; ++r)
                Cs[(wm + mi * 16 + quad * 4 + r) * 128 + col] = f2h(acc[mi][ni][r] + bv);
        }
    }
    __syncthreads();
    u16* O = (z == 0) ? qo : ko;
    int row = tid >> 1, halfc = tid & 1;
    int gr = m0 + row;
    if (gr < 12608) {
        int bb = gr / 197, ii = gr - bb * 197;
        int h = (n0 >> 6) + halfc;
        u16* dst = O + ((size_t)(bb * 12 + h) * 197 + ii) * 64;
        const u16* src = &Cs[row * 128 + halfc * 64];
        #pragma unroll
        for (int e = 0; e < 8; ++e)
            *(uint4*)(dst + e * 8) = *(const uint4*)(src + e * 8);
    }
}

// ---------------------------------------------------------------------------
// Fused attention, single-pass f16 MFMA, register-resident scores.
// XCD-grouped: 4 qt-blocks of one bh run adjacent on one XCD.
// K staged to LDS once per block via REG-STAGING (kreg[4] -> ds_write,
// stride-72 pad): R9 A/B showed this beats global_load_lds-direct here
// (89.5 vs 94 us) -- with gload_lds every wave drains vmcnt(0) at the
// phase-0 barrier; reg-staged waves complete loads independently.
// iRPE key bias via K-augmentation (khot one-hot MFMA), khot register-
// prefetched (R5 lesson). launch_bounds 2nd arg = min BLOCKS/CU here.
// ---------------------------------------------------------------------------
__global__ __launch_bounds__(512, 3) void attn_mfma(
    const u16* __restrict__ qh, const u16* __restrict__ kh,
    const u16* __restrict__ tk, const u16* __restrict__ vt,
    const u16* __restrict__ gt, const u16* __restrict__ khot,
    u16* __restrict__ oh)
{
    __shared__ u16 Ph[64 * 296];      // 37888 B; first used as Kst[224][72] = 32256 B
    __shared__ float BsT[64 * 36];    // 9216 B: phase A = Tvh f16; phase B = Bs f32
    __shared__ float red[64 * 4];     // [m][max0,max1,sum0,sum1]
    u16* Tvh16 = (u16*)BsT;           // 64*68 u16 = 8704 B
    u16* Kst = Ph;                    // overlay: K staging, dead before first Ph write

    const int p = blockIdx.x;
    const int xcd = p & 7, s = p >> 3;
    const int bh = xcd * 96 + (s >> 2);
    const int qt = s & 3;
    const int I0 = qt * 64;
    const int tid = threadIdx.x;
    const int w = tid >> 6, lane = tid & 63, quad = lane >> 4, l16 = lane & 15;
    const int mf = w >> 1, nh = w & 1;
    const int mr0 = mf * 16;
    const size_t base = (size_t)bh * 197 * 64;
    const uint4 z4 = make_uint4(0, 0, 0, 0);

    // ---- issue Q A-frag loads + khot prefetch + K-stage loads (independent,
    //      in flight under phase 0's MFMAs)
    half8 qa[2];
    {
        int i = I0 + mr0 + l16;
        bool ok = i < 197;
        const u16* qp = qh + base + (size_t)i * 64 + quad * 8;
        #pragma unroll
        for (int kb = 0; kb < 2; ++kb) {
            uint4 a = ok ? *(const uint4*)(qp + kb * 32) : z4;
            *(uint4*)&qa[kb] = a;
        }
    }
    int jj[7];
    #pragma unroll
    for (int s1 = 0; s1 < 7; ++s1) jj[s1] = (nh * 7 + s1) * 16 + l16;
    half8 kfh[7];
    #pragma unroll
    for (int s1 = 0; s1 < 7; ++s1)
        kfh[s1] = ld_h8(khot + jj[s1] * 32 + quad * 8);
    // 224 rows x 8 uint4-chunks (8 u16 each) = 1792 slots
    uint4 kreg[4];
    #pragma unroll
    for (int t2 = 0; t2 < 4; ++t2) {
        int t = tid + t2 * 512;
        int row = t >> 3, chunk = t & 7;
        kreg[t2] = (t < 1792 && row < 197)
                 ? *(const uint4*)(kh + base + (size_t)row * 64 + chunk * 8) : z4;
    }

    // ---- phase 0: Tvh = Q @ rel_k tables (cols nh*32 .. nh*32+31), f16 store
    #pragma unroll
    for (int s2 = 0; s2 < 2; ++s2) {
        int c = (nh * 2 + s2) * 16 + l16;
        f32x4 acc = (f32x4){0, 0, 0, 0};
        #pragma unroll
        for (int kb = 0; kb < 2; ++kb) {
            half8 th = ld_h8(tk + c * 64 + kb * 32 + quad * 8);
            acc = MFMA_H(qa[kb], th, acc, 0, 0, 0);
        }
        #pragma unroll
        for (int r = 0; r < 4; ++r)
            Tvh16[(mr0 + quad * 4 + r) * 68 + c] = f2h(acc[r]);
    }

    // ---- K -> LDS (rows 197..223 zeroed; phase-1 j reads reach 223)
    #pragma unroll
    for (int t2 = 0; t2 < 4; ++t2) {
        int t = tid + t2 * 512;
        if (t < 1792) {
            int row = t >> 3, chunk = t & 7;
            *(uint4*)&Kst[row * 72 + chunk * 8] = kreg[t2];
        }
    }
    __syncthreads();   // Kst + Tvh visible

    // ---- build augmented-Q frag from Tvh (row-gathered rel-k bias coeffs)
    half8 qa2;
    {
        int m = mr0 + l16;
        int i = I0 + m;
        u16 vals[8];
        if (i >= 1 && i < 197) {
            int qi = i - 1;
            int iv = qi / 14, ih = qi - iv * 14;
            #pragma unroll
            for (int e = 0; e < 8; ++e) {
                int c = quad * 8 + e;
                u16 v = 0;
                if (c < 14)      v = Tvh16[m * 68 + (c - iv + 15)];
                else if (c < 28) v = Tvh16[m * 68 + 32 + ((c - 14) - ih + 15)];
                vals[e] = v;
            }
        } else {
            #pragma unroll
            for (int e = 0; e < 8; ++e) vals[e] = 0;
        }
        *(uint4*)&qa2 = *(uint4*)vals;
    }

    // ---- phase 1: S = Q.K^T + bias, all MFMA (7 n-frags; 3 kb each;
    //      khot consumed from registers, LAST in each chain)
    f32x4 sacc[7];
    #pragma unroll
    for (int s1 = 0; s1 < 7; ++s1) {
        int j = jj[s1];
        f32x4 c = MFMA_H(qa[0], ld_h8(&Kst[j * 72 + quad * 8]),
                         (f32x4){0, 0, 0, 0}, 0, 0, 0);
        c = MFMA_H(qa[1], ld_h8(&Kst[j * 72 + 32 + quad * 8]), c, 0, 0, 0);
        c = MFMA_H(qa2, kfh[s1], c, 0, 0, 0);
        sacc[s1] = c;
    }

    // ---- partial row max -> red (scale once after max; padded cols are 0)
    #pragma unroll
    for (int r = 0; r < 4; ++r) {
        float mx = sacc[0][r];
        #pragma unroll
        for (int s1 = 1; s1 < 7; ++s1) mx = fmaxf(mx, sacc[s1][r]);
        mx *= SCALE_;
        #pragma unroll
        for (int off = 1; off < 16; off <<= 1) mx = fmaxf(mx, __shfl_xor(mx, off, 64));
        if (l16 == 0) red[(mr0 + quad * 4 + r) * 4 + nh] = mx;
    }
    __syncthreads();   // red(max) ready; Kst dead beyond this point

    // ---- exp + partial sums + write Ph (unnormalized p), zero cols 208..223
    #pragma unroll
    for (int r = 0; r < 4; ++r) {
        int m = mr0 + quad * 4 + r;
        float M = fmaxf(red[m * 4], red[m * 4 + 1]);
        float sum = 0.f;
        #pragma unroll
        for (int s1 = 0; s1 < 7; ++s1) {
            float pv = (jj[s1] < 197) ? __expf(sacc[s1][r] * SCALE_ - M) : 0.f;
            sacc[s1][r] = pv;
            sum += pv;
        }
        #pragma unroll
        for (int off = 1; off < 16; off <<= 1) sum += __shfl_xor(sum, off, 64);
        if (l16 == 0) red[m * 4 + 2 + nh] = sum;
    }
    #pragma unroll
    for (int s1 = 0; s1 < 7; ++s1) {
        int j = jj[s1];
        if (j < 208) {
            #pragma unroll
            for (int r = 0; r < 4; ++r)
                Ph[(mr0 + quad * 4 + r) * 296 + j] = f2h(sacc[s1][r]);
        }
    }
    #pragma unroll
    for (int t = 0; t < 2; ++t) {
        int ii2 = tid + t * 512;  // 1024 items: rows 0..63, cols 208..223
        Ph[(ii2 >> 4) * 296 + 208 + (ii2 & 15)] = 0;
    }
    __syncthreads();   // p cols 0..223 + sums ready

    // ---- Bs = P @ G^T via MFMA: Bs[m][g], g 0..13 = v-group sums,
    //      g 16..29 = h-group sums. Wave w: rows mr0..mr0+15, cols nh*16..+15.
    {
        f32x4 bacc = (f32x4){0, 0, 0, 0};
        #pragma unroll
        for (int ks = 0; ks < 7; ++ks) {
            half8 ap = ld_h8(&Ph[(mr0 + l16) * 296 + ks * 32 + quad * 8]);
            half8 gp = ld_h8(gt + (nh * 16 + l16) * 224 + ks * 32 + quad * 8);
            bacc = MFMA_H(ap, gp, bacc, 0, 0, 0);
        }
        #pragma unroll
        for (int r = 0; r < 4; ++r)
            BsT[(mr0 + quad * 4 + r) * 36 + nh * 16 + l16] = bacc[r];
    }
    // zero pad cols 272..287 while Bs lands
    for (int t = tid; t < 64 * 16; t += 512)
        Ph[(t >> 4) * 296 + 272 + (t & 15)] = 0;
    __syncthreads();   // Bs ready

    // ---- parallel scatter: Ph cols 208..271 (shifted histogram placement)
    #pragma unroll
    for (int t = 0; t < 8; ++t) {
        int idx = tid + t * 512;       // 4096 = 64 rows x 64 cols
        int m = idx >> 6, c = idx & 63;
        int i = I0 + m;
        float val;
        if (i == 0) {
            val = (c == 0 || c == 32) ? (red[m * 4 + 2] + red[m * 4 + 3]) : 0.f;
        } else {
            int qi = i - 1;
            int iv = qi / 14, ih = qi - (qi / 14) * 14;
            int r = c & 31;
            int bidx = r + ((c < 32) ? iv : ih) - 15;
            bool ok = (bidx >= 0) && (bidx <= 13) && (r < 30);
            int src = ((c < 32) ? 0 : 16) + min(13, max(0, bidx));
            val = ok ? BsT[m * 36 + src] : 0.f;
            if (r == 0) val += h2f(Ph[m * 296]);
        }
        Ph[m * 296 + 208 + c] = f2h(val);
    }
    __syncthreads();   // Ph complete

    // ---- phase 2: O = Ph @ vt^T (K=288), B-frags from global
    {
        f32x4 oacc[2] = {(f32x4){0, 0, 0, 0}, (f32x4){0, 0, 0, 0}};
        const u16* vb = vt + (size_t)bh * 64 * 288;
        #pragma unroll
        for (int ks = 0; ks < 9; ++ks) {
            half8 ap = ld_h8(&Ph[(mr0 + l16) * 296 + ks * 32 + quad * 8]);
            #pragma unroll
            for (int sd = 0; sd < 2; ++sd) {
                int d = (nh * 2 + sd) * 16 + l16;
                half8 bv = ld_h8(vb + (size_t)d * 288 + ks * 32 + quad * 8);
                oacc[sd] = MFMA_H(ap, bv, oacc[sd], 0, 0, 0);
            }
        }
        int b = bh / 12, h = bh - b * 12;
        float rl[4];
        #pragma unroll
        for (int r = 0; r < 4; ++r) {
            int m = mr0 + quad * 4 + r;
            rl[r] = 1.f / (red[m * 4 + 2] + red[m * 4 + 3]);
        }
        #pragma unroll
        for (int sd = 0; sd < 2; ++sd) {
            int d = (nh * 2 + sd) * 16 + l16;
            #pragma unroll
            for (int r = 0; r < 4; ++r) {
                int i = I0 + mr0 + quad * 4 + r;
                if (i < 197) {
                    oh[((size_t)(b * 197 + i)) * 768 + h * 64 + d] =
                        f2h(oacc[sd][r] * rl[r]);
                }
            }
        }
    }
}

// ---------------------------------------------------------------------------
extern "C" void kernel_launch(void* const* d_in, const int* in_sizes, int n_in,
                              void* d_out, int out_size, void* d_ws, size_t ws_size,
                              hipStream_t stream)
{
    const float* x   = (const float*)d_in[0];
    const float* wq  = (const float*)d_in[1];
    const float* bq  = (const float*)d_in[2];
    const float* wk  = (const float*)d_in[3];
    const float* bk  = (const float*)d_in[4];
    const float* wv  = (const float*)d_in[5];
    const float* bv  = (const float*)d_in[6];
    const float* wp  = (const float*)d_in[7];
    const float* bp  = (const float*)d_in[8];
    const float* rkv = (const float*)d_in[9];
    const float* rkh = (const float*)d_in[10];
    const float* rvv = (const float*)d_in[11];
    const float* rvh = (const float*)d_in[12];
    float* out = (float*)d_out;

    const size_t SZX = (size_t)12608 * 768;
    const size_t SZW = (size_t)768 * 768;
    const size_t SZVT = (size_t)768 * 64 * 288;

    u16* xh  = (u16*)d_ws;
    u16* qh_ = xh + SZX;
    u16* kh_ = qh_ + SZX;
    u16* vt  = kh_ + SZX;
    u16* wt  = vt + SZVT;
    u16* wqh = wt;
    u16* wkh = wt + SZW;
    u16* wvh = wt + 2 * SZW;
    u16* wph = wt + 3 * SZW;
    u16* tk  = wt + 4 * SZW;
    u16* gt  = tk + 4096;
    u16* khot = gt + 32 * 224;
    u16* oh_ = xh;   // overlay: x dead after QKV projection

    // all preps fused: 4728 + 576 + 16 + 28 + 28 + 768 = 6144 blocks
    prep_all<<<6144, 256, 0, stream>>>(
        x, wq, wk, wv, wp, rkv, rkh, rvv, rvh,
        xh, wqh, wkh, wvh, wph, tk, gt, khot, vt);

    // QKV: 8 XCDs * 13 m-slots * (6n * 3z) = 1872 blocks; V lands in vt
    gemm_f16<<<1872, 256, 0, stream>>>(
        xh, wqh, wkh, wvh, bq, bk, bv, qh_, kh_, vt, nullptr, 3, 0);

    attn_mfma<<<3072, 512, 0, stream>>>(qh_, kh_, tk, vt, gt, khot, oh_);

    // proj: 8 * 13 * 6 = 624 blocks
    gemm_f16<<<624, 256, 0, stream>>>(
        oh_, wph, wph, wph, bp, bp, bp, nullptr, nullptr, nullptr, out, 1, 1);
}